// Round 5
// baseline (194.611 us; speedup 1.0000x reference)
//
#include <hip/hip_runtime.h>
#include <hip/hip_bf16.h>
#include <math.h>

#define NB  32
#define NS  4096
#define ND  64
#define NKC 256

// proj tiling: 512 blocks x 256 threads, block tile 64kc x 64d, K split in 2,
// double-buffered LDS, B-prefetch depth 2.
#define BK    128   // K (seq) step per iteration
#define KHALF 2048
#define NIT   16    // KHALF / BK
#define ASA   132   // As row stride (shorts): 128 data + 4 pad
#define ASB   132   // Bs row stride (shorts)

// attn_fused LDS strides
#define QSTR  72
#define PBSTR 264
#define VSTR  264

typedef __attribute__((ext_vector_type(8))) short short8;
typedef __attribute__((ext_vector_type(4))) float f32x4;

__device__ __forceinline__ short f2bf(float f) {
    union { float f; unsigned u; } v; v.f = f;
    return (short)((v.u + 0x7FFFu + ((v.u >> 16) & 1u)) >> 16);  // RTNE
}

// ---------------------------------------------------------------------------
// proj v5: split-K=2, no atomics, DOUBLE-BUFFERED LDS (1 barrier/iter),
// B-prefetch depth 2. 512 blocks x 256 thr = 2 blocks/CU (8 waves/CU);
// co-resident blocks are barrier-independent.
//
// bid = gq*32 + mt*8 + r8; grp = gq*8 + r8 = ((b*2+mm)*2+kh):
//  - 4 mt-sharers of one B half-slab share bid%8 -> same XCD: B fetched
//    once per XCD, L2-served to 4 sharers.
//  - r8 fixes (kh, mm): each XCD streams one matrix & one K-half; its
//    A working set (256 x 2048 fp32 = 2 MB) is L2/L3-resident.
// A converted fp32->bf16 in staging (no prep kernel). Partial sums ->
// plain stores into per-half buffers; attn folds the two halves.
// ---------------------------------------------------------------------------
__global__ __launch_bounds__(256, 2) void proj_sk(
    const float* __restrict__ Ew, const float* __restrict__ Fw,
    const float* __restrict__ K, const float* __restrict__ V,
    float* __restrict__ KeTa, float* __restrict__ Vfa,
    float* __restrict__ KeTb, float* __restrict__ Vfb)
{
    const int bid = blockIdx.x;
    const int r8 = bid & 7, mt = (bid >> 3) & 3, gq = bid >> 5;  // gq 0..15
    const int grp = gq * 8 + r8;                                 // 0..127
    const int kh = grp & 1, mm = (grp >> 1) & 1, b = grp >> 2;

    const float* __restrict__ Ab = mm ? Fw : Ew;    // [256][4096] fp32
    const float* __restrict__ Bg = mm ? V  : K;     // [B][4096][64] fp32
    float* __restrict__ Cout = kh ? (mm ? Vfb : KeTb) : (mm ? Vfa : KeTa);

    const int t = threadIdx.x, wave = t >> 6, lane = t & 63;
    const int lm = lane & 15, g4 = lane >> 4;
    __shared__ short As[2][64 * ASA];   // 2 x 16896 B
    __shared__ short Bs[2][64 * ASB];   // 2 x 16896 B
    const size_t bBase = (size_t)b * NS * ND;
    const size_t aBase = (size_t)mt * 64 * NS;
    const int rA = t >> 4, jA = t & 15;  // A staging: 16 rows/pass, 16 col-octets
    const int dB = t & 31, sB = t >> 5;  // B staging: d-pair, s-octet group

    f32x4 acc[4];
#pragma unroll
    for (int nt = 0; nt < 4; ++nt) acc[nt] = (f32x4){0.f, 0.f, 0.f, 0.f};

    float4 paf[8];             // A prefetch (fp32), depth 1
    float2 pbA[16], pbB[16];   // B prefetch, depth 2 (ping-pong sets)

    const int sBeg = kh * KHALF;

    auto loadA = [&](int s) {
#pragma unroll
        for (int i = 0; i < 4; ++i) {
            paf[2 * i]     = *(const float4*)&Ab[aBase + (size_t)(i * 16 + rA) * NS + s + jA * 8];
            paf[2 * i + 1] = *(const float4*)&Ab[aBase + (size_t)(i * 16 + rA) * NS + s + jA * 8 + 4];
        }
    };
    auto loadB = [&](float2* pb, int s) {
#pragma unroll
        for (int h = 0; h < 2; ++h)
#pragma unroll
            for (int i = 0; i < 8; ++i)
                pb[h * 8 + i] = *(const float2*)&Bg[bBase + (size_t)(s + h * 64 + sB * 8 + i) * ND + dB * 2];
    };
    auto stage = [&](int buf, const float2* pb) {
#pragma unroll
        for (int i = 0; i < 4; ++i) {
            short8 w;
            w[0] = f2bf(paf[2 * i].x);     w[1] = f2bf(paf[2 * i].y);
            w[2] = f2bf(paf[2 * i].z);     w[3] = f2bf(paf[2 * i].w);
            w[4] = f2bf(paf[2 * i + 1].x); w[5] = f2bf(paf[2 * i + 1].y);
            w[6] = f2bf(paf[2 * i + 1].z); w[7] = f2bf(paf[2 * i + 1].w);
            *(short8*)&As[buf][(i * 16 + rA) * ASA + jA * 8] = w;
        }
#pragma unroll
        for (int h = 0; h < 2; ++h) {
            short8 w0, w1;
#pragma unroll
            for (int i = 0; i < 8; ++i) {
                w0[i] = f2bf(pb[h * 8 + i].x);
                w1[i] = f2bf(pb[h * 8 + i].y);
            }
            *(short8*)&Bs[buf][(dB * 2 + 0) * ASB + h * 64 + sB * 8] = w0;
            *(short8*)&Bs[buf][(dB * 2 + 1) * ASB + h * 64 + sB * 8] = w1;
        }
    };
    auto domfma = [&](int buf) {
#pragma unroll
        for (int ks = 0; ks < BK; ks += 32) {
            short8 aF = *(const short8*)&As[buf][(wave * 16 + lm) * ASA + ks + g4 * 8];
#pragma unroll
            for (int nt = 0; nt < 4; ++nt) {
                short8 bF = *(const short8*)&Bs[buf][(nt * 16 + lm) * ASB + ks + g4 * 8];
                acc[nt] = __builtin_amdgcn_mfma_f32_16x16x32_bf16(aF, bF, acc[nt], 0, 0, 0);
            }
        }
    };

    // ---- prologue: establish invariants for iter 0 ----
    // buf0 = tile0; paf = A(1); pbA = B(1); pbB = B(2)
    loadA(sBeg);
    loadB(pbA, sBeg);
    stage(0, pbA);
    loadA(sBeg + BK);
    loadB(pbA, sBeg + BK);
    loadB(pbB, sBeg + 2 * BK);
    __syncthreads();

    // ---- main loop: 16 iters, unrolled by 2, ONE barrier per iter ----
    // even iter i:  mfma(buf0); stage buf1 <- A(i+1),pbA=B(i+1); issue
    //               B(i+3)->pbA, A(i+2)->paf; barrier
    // odd  iter i:  mfma(buf1); stage buf0 <- A(i+1),pbB=B(i+1); issue
    //               B(i+3)->pbB, A(i+2)->paf; barrier
    for (int ip = 0; ip < NIT / 2; ++ip) {
        const int i0 = 2 * ip;
        // even iteration i0
        domfma(0);
        stage(1, pbA);
        if (i0 + 3 < NIT) loadB(pbA, sBeg + (i0 + 3) * BK);
        if (i0 + 2 < NIT) loadA(sBeg + (i0 + 2) * BK);
        __syncthreads();
        // odd iteration i0+1
        domfma(1);
        if (i0 + 2 < NIT) {
            stage(0, pbB);
            if (i0 + 4 < NIT) loadB(pbB, sBeg + (i0 + 4) * BK);
            if (i0 + 3 < NIT) loadA(sBeg + (i0 + 3) * BK);
            __syncthreads();
        }
    }

    // ---- epilogue: plain stores into this half's buffer ----
#pragma unroll
    for (int nt = 0; nt < 4; ++nt)
#pragma unroll
        for (int rr = 0; rr < 4; ++rr) {
            int kc = mt * 64 + wave * 16 + g4 * 4 + rr;
            Cout[((size_t)b * NKC + kc) * ND + nt * 16 + lm] = acc[nt][rr];
        }
}

// ---------------------------------------------------------------------------
// attn_fused (halves folded): reads KeTa+KeTb / Vfa+Vfb and sums in registers
// (identical arithmetic to the old reduce2 pass). x<8 -> MFMA attention rows
// x*32..+31; x>=8 -> mean-broadcast, 64 rows/block. grid (68, 32).
// ---------------------------------------------------------------------------
__global__ __launch_bounds__(256) void attn_fused(
    const float* __restrict__ Q,
    const float* __restrict__ KeTa, const float* __restrict__ Vfa,
    const float* __restrict__ KeTb, const float* __restrict__ Vfb,
    const float* __restrict__ Eb,  const float* __restrict__ Fb,
    float* __restrict__ out)
{
    const int x = blockIdx.x, b = blockIdx.y, t = threadIdx.x;

    if (x >= 8) {
        // rows >= 256 fully masked -> uniform softmax -> mean_k (Vf[k,:]+Fb[k])
        __shared__ float pq[16][64];
        __shared__ float mv[64];
        const int kg = t >> 4, dq = t & 15;
        float4 s4 = (float4){0.f, 0.f, 0.f, 0.f};
        for (int p = 0; p < 16; ++p) {
            int k = p * 16 + kg;
            float4 v = *(const float4*)&Vfa[((size_t)b * NKC + k) * ND + dq * 4];
            float4 u = *(const float4*)&Vfb[((size_t)b * NKC + k) * ND + dq * 4];
            float fb = Fb[k];
            s4.x += (v.x + u.x) + fb; s4.y += (v.y + u.y) + fb;
            s4.z += (v.z + u.z) + fb; s4.w += (v.w + u.w) + fb;
        }
        *(float4*)&pq[kg][dq * 4] = s4;
        __syncthreads();
        if (t < 64) {
            float m = 0.f;
#pragma unroll
            for (int i = 0; i < 16; ++i) m += pq[i][t];
            mv[t] = m * (1.f / 256.f);
        }
        __syncthreads();
        const int r0 = 256 + (x - 8) * 64;
#pragma unroll
        for (int i = 0; i < 4; ++i) {      // 4*256 float4 = 64 rows
            int idx = i * 256 + t, row = idx >> 4, q = idx & 15;
            *(float4*)&out[((size_t)b * NS + r0 + row) * ND + q * 4] =
                *(const float4*)&mv[q * 4];
        }
        return;
    }

    const int s0 = x * 32;
    const int wave = t >> 6, lane = t & 63, lm = lane & 15, g = lane >> 4;
    __shared__ short Qs[32 * QSTR];     //  4.6 KB
    __shared__ short PsB[32 * PBSTR];   // 16.9 KB
    __shared__ short VfT[64 * VSTR];    // 33.8 KB
    __shared__ float rsums[32][4];      // [row][wave]

    // stage Q rows -> bf16
    {
        int row = t >> 3, dq = t & 7;
        size_t off = ((size_t)b * NS + s0 + row) * ND + dq * 8;
        float4 q0 = *(const float4*)&Q[off], q1 = *(const float4*)&Q[off + 4];
        short8 w;
        w[0] = f2bf(q0.x); w[1] = f2bf(q0.y); w[2] = f2bf(q0.z); w[3] = f2bf(q0.w);
        w[4] = f2bf(q1.x); w[5] = f2bf(q1.y); w[6] = f2bf(q1.z); w[7] = f2bf(q1.w);
        *(short8*)&Qs[row * QSTR + dq * 8] = w;
    }
    // stage VfT[d][k] = bf16(Vfa[k][d]+Vfb[k][d] + Fb[k]); 4 passes of 64 k-rows
    {
        const int dB = t & 31, sB = t >> 5;
#pragma unroll
        for (int pass = 0; pass < 4; ++pass) {
            int kb = pass * 64 + sB * 8;
            float2 v[8], u[8]; float fb[8];
#pragma unroll
            for (int i = 0; i < 8; ++i) {
                v[i]  = *(const float2*)&Vfa[((size_t)b * NKC + kb + i) * ND + dB * 2];
                u[i]  = *(const float2*)&Vfb[((size_t)b * NKC + kb + i) * ND + dB * 2];
                fb[i] = Fb[kb + i];
            }
            short8 w0, w1;
#pragma unroll
            for (int i = 0; i < 8; ++i) {
                w0[i] = f2bf((v[i].x + u[i].x) + fb[i]);
                w1[i] = f2bf((v[i].y + u[i].y) + fb[i]);
            }
            *(short8*)&VfT[(dB * 2 + 0) * VSTR + kb] = w0;
            *(short8*)&VfT[(dB * 2 + 1) * VSTR + kb] = w1;
        }
    }
    __syncthreads();

    // phase 1: P = Q*(Ke+Eb)^T/8; wave w -> col range [w*64, w*64+64)
    f32x4 accP[2][4];
#pragma unroll
    for (int rt = 0; rt < 2; ++rt)
#pragma unroll
        for (int kk = 0; kk < 4; ++kk) accP[rt][kk] = (f32x4){0.f, 0.f, 0.f, 0.f};
#pragma unroll
    for (int kk = 0; kk < 4; ++kk) {
        int kt = wave * 4 + kk;
        float ebv = Eb[kt * 16 + lm];
#pragma unroll
        for (int ks2 = 0; ks2 < 2; ++ks2) {
            const size_t koff = ((size_t)b * NKC + kt * 16 + lm) * ND + ks2 * 32 + g * 8;
            float4 c0 = *(const float4*)&KeTa[koff], c1 = *(const float4*)&KeTa[koff + 4];
            float4 e0 = *(const float4*)&KeTb[koff], e1 = *(const float4*)&KeTb[koff + 4];
            short8 bf;
            bf[0] = f2bf((c0.x + e0.x) + ebv); bf[1] = f2bf((c0.y + e0.y) + ebv);
            bf[2] = f2bf((c0.z + e0.z) + ebv); bf[3] = f2bf((c0.w + e0.w) + ebv);
            bf[4] = f2bf((c1.x + e1.x) + ebv); bf[5] = f2bf((c1.y + e1.y) + ebv);
            bf[6] = f2bf((c1.z + e1.z) + ebv); bf[7] = f2bf((c1.w + e1.w) + ebv);
#pragma unroll
            for (int rt = 0; rt < 2; ++rt) {
                short8 aq = *(const short8*)&Qs[(rt * 16 + lm) * QSTR + ks2 * 32 + g * 8];
                accP[rt][kk] = __builtin_amdgcn_mfma_f32_16x16x32_bf16(aq, bf, accP[rt][kk], 0, 0, 0);
            }
        }
    }
    // exp (max-free: scores ~ N(0,1), no overflow) + per-row partial sums
#pragma unroll
    for (int rt = 0; rt < 2; ++rt)
#pragma unroll
        for (int r = 0; r < 4; ++r) {
            float s = 0.f;
            int rowg = s0 + rt * 16 + g * 4 + r;
#pragma unroll
            for (int kk = 0; kk < 4; ++kk) {
                int col = wave * 64 + kk * 16 + lm;
                float e = (col >= rowg) ? __expf(accP[rt][kk][r] * 0.125f) : 0.f;
                accP[rt][kk][r] = e;
                s += e;
            }
#pragma unroll
            for (int off = 1; off <= 8; off <<= 1) s += __shfl_xor(s, off, 64);
            if (lm == 0) rsums[rt * 16 + g * 4 + r][wave] = s;
        }
    __syncthreads();
    // normalize -> PsB bf16
#pragma unroll
    for (int rt = 0; rt < 2; ++rt)
#pragma unroll
        for (int r = 0; r < 4; ++r) {
            float4 rs = *(const float4*)&rsums[rt * 16 + g * 4 + r][0];
            float inv = 1.f / (rs.x + rs.y + rs.z + rs.w);
#pragma unroll
            for (int kk = 0; kk < 4; ++kk)
                PsB[(rt * 16 + g * 4 + r) * PBSTR + wave * 64 + kk * 16 + lm] =
                    f2bf(accP[rt][kk][r] * inv);
        }
    __syncthreads();

    // phase 2: out = P * VfT; k < 32x provably zero -> start at ks = x
    f32x4 oa[2];
    oa[0] = (f32x4){0.f, 0.f, 0.f, 0.f};
    oa[1] = (f32x4){0.f, 0.f, 0.f, 0.f};
    for (int ks = x; ks < 8; ++ks) {
        short8 bv = *(const short8*)&VfT[(wave * 16 + lm) * VSTR + ks * 32 + g * 8];
#pragma unroll
        for (int rt = 0; rt < 2; ++rt) {
            short8 av = *(const short8*)&PsB[(rt * 16 + lm) * PBSTR + ks * 32 + g * 8];
            oa[rt] = __builtin_amdgcn_mfma_f32_16x16x32_bf16(av, bv, oa[rt], 0, 0, 0);
        }
    }
#pragma unroll
    for (int rt = 0; rt < 2; ++rt)
#pragma unroll
        for (int r = 0; r < 4; ++r)
            out[((size_t)b * NS + s0 + rt * 16 + g * 4 + r) * ND + wave * 16 + lm] = oa[rt][r];
}

extern "C" void kernel_launch(void* const* d_in, const int* in_sizes, int n_in,
                              void* d_out, int out_size, void* d_ws, size_t ws_size,
                              hipStream_t stream) {
    (void)in_sizes; (void)n_in; (void)out_size; (void)ws_size;
    const float* Q  = (const float*)d_in[0];
    const float* K  = (const float*)d_in[1];
    const float* V  = (const float*)d_in[2];
    const float* Ew = (const float*)d_in[3];
    const float* Eb = (const float*)d_in[4];
    const float* Fw = (const float*)d_in[5];
    const float* Fb = (const float*)d_in[6];
    float* out = (float*)d_out;

    const size_t nKe = (size_t)NB * NKC * ND;       // 524288 floats (2 MB)
    float* base = (float*)d_ws;
    float* KeTa = base;                             // [0, 2 MB)
    float* Vfa  = base + nKe;                       // [2, 4 MB)
    float* KeTb = base + 2 * nKe;                   // [4, 6 MB)
    float* Vfb  = base + 3 * nKe;                   // [6, 8 MB)

    proj_sk<<<dim3(512), 256, 0, stream>>>(Ew, Fw, K, V, KeTa, Vfa, KeTb, Vfb);
    attn_fused<<<dim3(68, NB), 256, 0, stream>>>(Q, KeTa, Vfa, KeTb, Vfb,
                                                 Eb, Fb, out);
}

// Round 6
// 188.978 us; speedup vs baseline: 1.0298x; 1.0298x over previous
//
#include <hip/hip_runtime.h>
#include <hip/hip_bf16.h>
#include <math.h>

#define NB  32
#define NS  4096
#define ND  64
#define NKC 256

// proj tiling (R4-proven): 512 blocks x 256 threads, tile 64kc x 64d, split-K=2
#define BK    128
#define KHALF 2048
#define ASA   132   // As row stride (shorts): 128 data + 4 pad
#define ASB   132   // Bs row stride (shorts)

// attn_fused LDS strides
#define QSTR  72
#define PBSTR 264
#define VSTR  264

typedef __attribute__((ext_vector_type(8))) short short8;
typedef __attribute__((ext_vector_type(4))) short short4v;
typedef __attribute__((ext_vector_type(4))) float f32x4;

__device__ __forceinline__ short f2bf(float f) {
    union { float f; unsigned u; } v; v.f = f;
    return (short)((v.u + 0x7FFFu + ((v.u >> 16) & 1u)) >> 16);  // RTNE
}

// ---------------------------------------------------------------------------
// prep (ws>=12MB only): convert Ew/Fw fp32 -> bf16.
// ---------------------------------------------------------------------------
__global__ __launch_bounds__(256) void prep(
    const float* __restrict__ Ew, const float* __restrict__ Fw,
    short* __restrict__ EwB, short* __restrict__ FwB)
{
    const int gid = blockIdx.x * 256 + threadIdx.x;       // < 262144
    const int half = (NKC * NS) / 8;                      // 131072
    const float* src = (gid < half) ? Ew : Fw;
    short* dst       = (gid < half) ? EwB : FwB;
    const int i8 = (gid < half) ? gid : gid - half;
    float4 a = *(const float4*)&src[(size_t)i8 * 8];
    float4 c = *(const float4*)&src[(size_t)i8 * 8 + 4];
    short8 w;
    w[0] = f2bf(a.x); w[1] = f2bf(a.y); w[2] = f2bf(a.z); w[3] = f2bf(a.w);
    w[4] = f2bf(c.x); w[5] = f2bf(c.y); w[6] = f2bf(c.z); w[7] = f2bf(c.w);
    *(short8*)&dst[(size_t)i8 * 8] = w;
}

// ---------------------------------------------------------------------------
// proj (R4 verbatim): split-K=2, no atomics, single-buffer 2-barrier loop.
// 512 blocks x 256 thr = 2 blocks/CU; co-resident blocks overlap stalls.
// bid = gq*32 + mt*8 + r8; grp = gq*8 + r8 = ((b*2+mm)*2+kh).
// ---------------------------------------------------------------------------
template <typename AT>
__global__ __launch_bounds__(256, 2) void proj_sk(
    const AT* __restrict__ EwX, const AT* __restrict__ FwX,
    const float* __restrict__ K, const float* __restrict__ V,
    float* __restrict__ KeTa, float* __restrict__ Vfa,
    float* __restrict__ KeTb, float* __restrict__ Vfb)
{
    const int bid = blockIdx.x;
    const int r8 = bid & 7, mt = (bid >> 3) & 3, gq = bid >> 5;  // gq 0..15
    const int grp = gq * 8 + r8;                                 // 0..127
    const int kh = grp & 1, mm = (grp >> 1) & 1, b = grp >> 2;

    const AT* __restrict__ Ab    = mm ? FwX : EwX;  // [256][4096]
    const float* __restrict__ Bg = mm ? V   : K;    // [B][4096][64] fp32
    float* __restrict__ Cout = kh ? (mm ? Vfb : KeTb) : (mm ? Vfa : KeTa);

    const int t = threadIdx.x, wave = t >> 6, lane = t & 63;
    const int lm = lane & 15, g4 = lane >> 4;
    __shared__ short As[64 * ASA];   // 16896 B
    __shared__ short Bs[64 * ASB];   // 16896 B
    const size_t bBase = (size_t)b * NS * ND;
    const size_t aBase = (size_t)mt * 64 * NS;
    const int rA = t >> 4, jA = t & 15;
    const int dB = t & 31, sB = t >> 5;

    f32x4 acc[4];
#pragma unroll
    for (int nt = 0; nt < 4; ++nt) acc[nt] = (f32x4){0.f, 0.f, 0.f, 0.f};

    short8 pa[4];
    float4 paf[8];
    float2 pb[16];

    const int sBeg = kh * KHALF, sEnd = sBeg + KHALF;

#pragma unroll
    for (int i = 0; i < 4; ++i) {
        if constexpr (sizeof(AT) == 2) {
            pa[i] = *(const short8*)&Ab[aBase + (size_t)(i * 16 + rA) * NS + sBeg + jA * 8];
        } else {
            paf[2 * i]     = *(const float4*)&Ab[aBase + (size_t)(i * 16 + rA) * NS + sBeg + jA * 8];
            paf[2 * i + 1] = *(const float4*)&Ab[aBase + (size_t)(i * 16 + rA) * NS + sBeg + jA * 8 + 4];
        }
    }
#pragma unroll
    for (int h = 0; h < 2; ++h)
#pragma unroll
        for (int i = 0; i < 8; ++i)
            pb[h * 8 + i] = *(const float2*)&Bg[bBase + (size_t)(sBeg + h * 64 + sB * 8 + i) * ND + dB * 2];

    for (int s0 = sBeg; s0 < sEnd; s0 += BK) {
#pragma unroll
        for (int i = 0; i < 4; ++i) {
            if constexpr (sizeof(AT) == 2) {
                *(short8*)&As[(i * 16 + rA) * ASA + jA * 8] = pa[i];
            } else {
                short8 w;
                w[0] = f2bf(paf[2 * i].x);     w[1] = f2bf(paf[2 * i].y);
                w[2] = f2bf(paf[2 * i].z);     w[3] = f2bf(paf[2 * i].w);
                w[4] = f2bf(paf[2 * i + 1].x); w[5] = f2bf(paf[2 * i + 1].y);
                w[6] = f2bf(paf[2 * i + 1].z); w[7] = f2bf(paf[2 * i + 1].w);
                *(short8*)&As[(i * 16 + rA) * ASA + jA * 8] = w;
            }
        }
#pragma unroll
        for (int h = 0; h < 2; ++h) {
            short8 w0, w1;
#pragma unroll
            for (int i = 0; i < 8; ++i) {
                w0[i] = f2bf(pb[h * 8 + i].x);
                w1[i] = f2bf(pb[h * 8 + i].y);
            }
            *(short8*)&Bs[(dB * 2 + 0) * ASB + h * 64 + sB * 8] = w0;
            *(short8*)&Bs[(dB * 2 + 1) * ASB + h * 64 + sB * 8] = w1;
        }
        __syncthreads();

        if (s0 + BK < sEnd) {
            const int sn = s0 + BK;
#pragma unroll
            for (int i = 0; i < 4; ++i) {
                if constexpr (sizeof(AT) == 2) {
                    pa[i] = *(const short8*)&Ab[aBase + (size_t)(i * 16 + rA) * NS + sn + jA * 8];
                } else {
                    paf[2 * i]     = *(const float4*)&Ab[aBase + (size_t)(i * 16 + rA) * NS + sn + jA * 8];
                    paf[2 * i + 1] = *(const float4*)&Ab[aBase + (size_t)(i * 16 + rA) * NS + sn + jA * 8 + 4];
                }
            }
#pragma unroll
            for (int h = 0; h < 2; ++h)
#pragma unroll
                for (int i = 0; i < 8; ++i)
                    pb[h * 8 + i] = *(const float2*)&Bg[bBase + (size_t)(sn + h * 64 + sB * 8 + i) * ND + dB * 2];
        }

#pragma unroll
        for (int ks = 0; ks < BK; ks += 32) {
            short8 aF = *(const short8*)&As[(wave * 16 + lm) * ASA + ks + g4 * 8];
#pragma unroll
            for (int nt = 0; nt < 4; ++nt) {
                short8 bF = *(const short8*)&Bs[(nt * 16 + lm) * ASB + ks + g4 * 8];
                acc[nt] = __builtin_amdgcn_mfma_f32_16x16x32_bf16(aF, bF, acc[nt], 0, 0, 0);
            }
        }
        __syncthreads();
    }

#pragma unroll
    for (int nt = 0; nt < 4; ++nt)
#pragma unroll
        for (int rr = 0; rr < 4; ++rr) {
            int kc = mt * 64 + wave * 16 + g4 * 4 + rr;
            Cout[((size_t)b * NKC + kc) * ND + nt * 16 + lm] = acc[nt][rr];
        }
}

// ---------------------------------------------------------------------------
// attn_fused v2: 512 threads / 8 waves — halves each wave's serial chain.
// Folds the split-K halves (KeTa+KeTb, Vfa+Vfb) in registers.
// x<8: phase1 wave w owns cols [w*32,+32) (2 kk-tiles, 8 MFMA);
//      phase2 wave w owns (row-tile w>>2, d-tile w&3) (1 MFMA per ks).
// x>=8: mean-broadcast, 64 rows/block. grid (68, 32).
// ---------------------------------------------------------------------------
__global__ __launch_bounds__(512) void attn_fused(
    const float* __restrict__ Q,
    const float* __restrict__ KeTa, const float* __restrict__ Vfa,
    const float* __restrict__ KeTb, const float* __restrict__ Vfb,
    const float* __restrict__ Eb,  const float* __restrict__ Fb,
    float* __restrict__ out)
{
    const int x = blockIdx.x, b = blockIdx.y, t = threadIdx.x;

    if (x >= 8) {
        // rows >= 256 fully masked -> uniform softmax -> mean_k (Vf[k,:]+Fb[k])
        __shared__ float pq[32][64];
        __shared__ float mv[64];
        const int kg = t >> 4, dq = t & 15;       // kg 0..31
        float4 s4 = (float4){0.f, 0.f, 0.f, 0.f};
#pragma unroll
        for (int p = 0; p < 8; ++p) {
            int k = p * 32 + kg;
            float4 v = *(const float4*)&Vfa[((size_t)b * NKC + k) * ND + dq * 4];
            float4 u = *(const float4*)&Vfb[((size_t)b * NKC + k) * ND + dq * 4];
            float fb = Fb[k];
            s4.x += (v.x + u.x) + fb; s4.y += (v.y + u.y) + fb;
            s4.z += (v.z + u.z) + fb; s4.w += (v.w + u.w) + fb;
        }
        *(float4*)&pq[kg][dq * 4] = s4;
        __syncthreads();
        if (t < 64) {
            float m = 0.f;
#pragma unroll
            for (int i = 0; i < 32; ++i) m += pq[i][t];
            mv[t] = m * (1.f / 256.f);
        }
        __syncthreads();
        const int r0 = 256 + (x - 8) * 64;
#pragma unroll
        for (int i = 0; i < 2; ++i) {      // 2*512 float4 = 64 rows
            int idx = i * 512 + t, row = idx >> 4, q = idx & 15;
            *(float4*)&out[((size_t)b * NS + r0 + row) * ND + q * 4] =
                *(const float4*)&mv[q * 4];
        }
        return;
    }

    const int s0 = x * 32;
    const int wave = t >> 6, lane = t & 63, lm = lane & 15, g = lane >> 4;
    __shared__ short Qs[32 * QSTR];     //  4.6 KB
    __shared__ short PsB[32 * PBSTR];   // 16.9 KB
    __shared__ short VfT[64 * VSTR];    // 33.8 KB
    __shared__ float rsums[32][8];      // [row][wave]

    // stage Q rows -> bf16 (512 threads, 4 floats each)
    {
        int row = t >> 4, dq = t & 15;
        size_t off = ((size_t)b * NS + s0 + row) * ND + dq * 4;
        float4 q0 = *(const float4*)&Q[off];
        short4v w;
        w[0] = f2bf(q0.x); w[1] = f2bf(q0.y); w[2] = f2bf(q0.z); w[3] = f2bf(q0.w);
        *(short4v*)&Qs[row * QSTR + dq * 4] = w;
    }
    // stage VfT[d][k] = bf16(Vfa+Vfb + Fb); 2 passes of 128 k-rows
    {
        const int dB = t & 31, sB = t >> 5;   // sB 0..15
#pragma unroll
        for (int pass = 0; pass < 2; ++pass) {
            int kb = pass * 128 + sB * 8;
            float2 v[8], u[8]; float fb[8];
#pragma unroll
            for (int i = 0; i < 8; ++i) {
                v[i]  = *(const float2*)&Vfa[((size_t)b * NKC + kb + i) * ND + dB * 2];
                u[i]  = *(const float2*)&Vfb[((size_t)b * NKC + kb + i) * ND + dB * 2];
                fb[i] = Fb[kb + i];
            }
            short8 w0, w1;
#pragma unroll
            for (int i = 0; i < 8; ++i) {
                w0[i] = f2bf((v[i].x + u[i].x) + fb[i]);
                w1[i] = f2bf((v[i].y + u[i].y) + fb[i]);
            }
            *(short8*)&VfT[(dB * 2 + 0) * VSTR + kb] = w0;
            *(short8*)&VfT[(dB * 2 + 1) * VSTR + kb] = w1;
        }
    }
    __syncthreads();

    // phase 1: P = Q*(Ke+Eb)^T/8; wave w -> cols [w*32, w*32+32)
    f32x4 accP[2][2];
#pragma unroll
    for (int rt = 0; rt < 2; ++rt)
#pragma unroll
        for (int kk = 0; kk < 2; ++kk) accP[rt][kk] = (f32x4){0.f, 0.f, 0.f, 0.f};
#pragma unroll
    for (int kk = 0; kk < 2; ++kk) {
        int kt = wave * 2 + kk;                  // 0..15
        float ebv = Eb[kt * 16 + lm];
#pragma unroll
        for (int ks2 = 0; ks2 < 2; ++ks2) {
            const size_t koff = ((size_t)b * NKC + kt * 16 + lm) * ND + ks2 * 32 + g * 8;
            float4 c0 = *(const float4*)&KeTa[koff], c1 = *(const float4*)&KeTa[koff + 4];
            float4 e0 = *(const float4*)&KeTb[koff], e1 = *(const float4*)&KeTb[koff + 4];
            short8 bf;
            bf[0] = f2bf((c0.x + e0.x) + ebv); bf[1] = f2bf((c0.y + e0.y) + ebv);
            bf[2] = f2bf((c0.z + e0.z) + ebv); bf[3] = f2bf((c0.w + e0.w) + ebv);
            bf[4] = f2bf((c1.x + e1.x) + ebv); bf[5] = f2bf((c1.y + e1.y) + ebv);
            bf[6] = f2bf((c1.z + e1.z) + ebv); bf[7] = f2bf((c1.w + e1.w) + ebv);
#pragma unroll
            for (int rt = 0; rt < 2; ++rt) {
                short8 aq = *(const short8*)&Qs[(rt * 16 + lm) * QSTR + ks2 * 32 + g * 8];
                accP[rt][kk] = __builtin_amdgcn_mfma_f32_16x16x32_bf16(aq, bf, accP[rt][kk], 0, 0, 0);
            }
        }
    }
    // exp (max-free) + per-row partial sums
#pragma unroll
    for (int rt = 0; rt < 2; ++rt)
#pragma unroll
        for (int r = 0; r < 4; ++r) {
            float s = 0.f;
            int rowg = s0 + rt * 16 + g * 4 + r;
#pragma unroll
            for (int kk = 0; kk < 2; ++kk) {
                int col = wave * 32 + kk * 16 + lm;
                float e = (col >= rowg) ? __expf(accP[rt][kk][r] * 0.125f) : 0.f;
                accP[rt][kk][r] = e;
                s += e;
            }
#pragma unroll
            for (int off = 1; off <= 8; off <<= 1) s += __shfl_xor(s, off, 64);
            if (lm == 0) rsums[rt * 16 + g * 4 + r][wave] = s;
        }
    __syncthreads();
    // normalize -> PsB bf16
#pragma unroll
    for (int rt = 0; rt < 2; ++rt)
#pragma unroll
        for (int r = 0; r < 4; ++r) {
            int row = rt * 16 + g * 4 + r;
            float4 ra = *(const float4*)&rsums[row][0];
            float4 rb = *(const float4*)&rsums[row][4];
            float inv = 1.f / (ra.x + ra.y + ra.z + ra.w + rb.x + rb.y + rb.z + rb.w);
#pragma unroll
            for (int kk = 0; kk < 2; ++kk)
                PsB[row * PBSTR + wave * 32 + kk * 16 + lm] =
                    f2bf(accP[rt][kk][r] * inv);
        }
    __syncthreads();

    // phase 2: out = P * VfT; wave w -> (row-tile w>>2, d-tile w&3);
    // k < 32x provably zero -> start at ks = x
    const int rt2 = wave >> 2, dt = wave & 3;
    f32x4 oa = (f32x4){0.f, 0.f, 0.f, 0.f};
    for (int ks = x; ks < 8; ++ks) {
        short8 bv = *(const short8*)&VfT[(dt * 16 + lm) * VSTR + ks * 32 + g * 8];
        short8 av = *(const short8*)&PsB[(rt2 * 16 + lm) * PBSTR + ks * 32 + g * 8];
        oa = __builtin_amdgcn_mfma_f32_16x16x32_bf16(av, bv, oa, 0, 0, 0);
    }
#pragma unroll
    for (int r = 0; r < 4; ++r)
        out[((size_t)b * NS + s0 + rt2 * 16 + g * 4 + r) * ND + dt * 16 + lm] = oa[r];
}

extern "C" void kernel_launch(void* const* d_in, const int* in_sizes, int n_in,
                              void* d_out, int out_size, void* d_ws, size_t ws_size,
                              hipStream_t stream) {
    (void)in_sizes; (void)n_in; (void)out_size;
    const float* Q  = (const float*)d_in[0];
    const float* K  = (const float*)d_in[1];
    const float* V  = (const float*)d_in[2];
    const float* Ew = (const float*)d_in[3];
    const float* Eb = (const float*)d_in[4];
    const float* Fw = (const float*)d_in[5];
    const float* Fb = (const float*)d_in[6];
    float* out = (float*)d_out;

    const size_t nKe = (size_t)NB * NKC * ND;       // 524288 floats (2 MB)
    float* base = (float*)d_ws;
    float* KeTa = base;                             // [0, 2 MB)
    float* Vfa  = base + nKe;                       // [2, 4 MB)
    float* KeTb = base + 2 * nKe;                   // [4, 6 MB)
    float* Vfb  = base + 3 * nKe;                   // [6, 8 MB)

    if (ws_size >= 12u * 1024 * 1024) {
        short* EwB = (short*)(base + 4 * nKe);      // [8, 10 MB)
        short* FwB = EwB + (size_t)NKC * NS;        // [10, 12 MB)
        prep<<<dim3(1024), 256, 0, stream>>>(Ew, Fw, EwB, FwB);
        proj_sk<short><<<dim3(512), 256, 0, stream>>>(EwB, FwB, K, V,
                                                      KeTa, Vfa, KeTb, Vfb);
    } else {
        proj_sk<float><<<dim3(512), 256, 0, stream>>>(Ew, Fw, K, V,
                                                      KeTa, Vfa, KeTb, Vfb);
    }
    attn_fused<<<dim3(68, NB), 512, 0, stream>>>(Q, KeTa, Vfa, KeTb, Vfb,
                                                 Eb, Fb, out);
}